// Round 1
// baseline (37.717 us; speedup 1.0000x reference)
//
#include <hip/hip_runtime.h>
#include <stdint.h>

#define BATCH 32
#define NH 12
#define SEQ 785
#define PN 784        // patch_num = SEQ - 1
#define HDIM 28       // ceil(sqrt(784)) = 28, 28*28 == 784
#define VOTE 24       // VOTE_PERHEAD
#define NCHUNK 13     // ceil(784 / 64)

// Monotonic float -> uint32 transform: k(a) > k(b) iff a > b (IEEE total order).
__device__ __forceinline__ uint32_t mono_key(float f) {
    uint32_t u = __float_as_uint(f);
    return (u & 0x80000000u) ? ~u : (u | 0x80000000u);
}

// Wave-wide (64-lane) max of a 64-bit key via butterfly shuffles (32-bit halves).
__device__ __forceinline__ uint64_t wave_max_u64(uint64_t v) {
    #pragma unroll
    for (int off = 32; off > 0; off >>= 1) {
        uint32_t lo = (uint32_t)v;
        uint32_t hi = (uint32_t)(v >> 32);
        uint32_t olo = __shfl_xor(lo, off, 64);
        uint32_t ohi = __shfl_xor(hi, off, 64);
        uint64_t o = ((uint64_t)ohi << 32) | (uint64_t)olo;
        if (o > v) v = o;
    }
    return v;
}

__launch_bounds__(768, 1)
__global__ void mhv_kernel(const float* __restrict__ x,
                           const float* __restrict__ kern,
                           float* __restrict__ out,
                           int select_num) {
    const int b    = blockIdx.x;
    const int tid  = threadIdx.x;
    const int wave = tid >> 6;
    const int lane = tid & 63;

    __shared__ int   cnt[PN];
    __shared__ float convf[PN];
    __shared__ float kl[9];

    for (int i = tid; i < PN; i += blockDim.x) cnt[i] = 0;
    if (tid < 9) kl[tid] = kern[tid];
    __syncthreads();

    // ---- Phase A: per-head top-24 vote (wave w == head w) -------------------
    {
        const int h = wave;  // 12 waves, 12 heads
        const size_t base = ((size_t)(b * NH + h) * SEQ) * SEQ + 1;  // x[b,h,0,1]

        uint64_t key[NCHUNK];
        #pragma unroll
        for (int k = 0; k < NCHUNK; ++k) {
            int idx = k * 64 + lane;
            if (idx < PN) {
                float v = x[base + idx];
                key[k] = ((uint64_t)mono_key(v) << 32) | (uint64_t)(uint32_t)(PN - 1 - idx);
            } else {
                key[k] = 0;
            }
        }

        for (int t = 0; t < VOTE; ++t) {
            uint64_t m = key[0];
            #pragma unroll
            for (int k = 1; k < NCHUNK; ++k) m = (key[k] > m) ? key[k] : m;
            m = wave_max_u64(m);                      // all lanes agree
            int idx = (PN - 1) - (int)(uint32_t)m;    // winning score index
            // clear winner (static register indexing only)
            if ((idx & 63) == lane) {
                int kk = idx >> 6;
                #pragma unroll
                for (int k = 0; k < NCHUNK; ++k)
                    if (k == kk) key[k] = 0;
                atomicAdd(&cnt[idx], 1);              // exactly one lane votes
            }
        }
    }
    __syncthreads();

    // ---- Phase B: 3x3 SAME conv on the 28x28 count grid; write output 1 ----
    float* out1 = out + BATCH * select_num;
    for (int i = tid; i < PN; i += blockDim.x) {
        int y = i / HDIM;
        int xx = i - y * HDIM;
        float s = 0.0f;
        #pragma unroll
        for (int dy = 0; dy < 3; ++dy) {
            int yy = y + dy - 1;
            if (yy < 0 || yy >= HDIM) continue;
            #pragma unroll
            for (int dx = 0; dx < 3; ++dx) {
                int xc = xx + dx - 1;
                if (xc < 0 || xc >= HDIM) continue;
                s += kl[dy * 3 + dx] * (float)cnt[yy * HDIM + xc];
            }
        }
        convf[i] = s;
        out1[(size_t)b * PN + i] = s;
    }
    __syncthreads();

    // ---- Phase C: stable descending top-select_num of conv counts ----------
    // argsort(-count) stable == value desc, index asc -> same 64-bit key trick.
    if (wave == 0) {
        uint64_t key[NCHUNK];
        #pragma unroll
        for (int k = 0; k < NCHUNK; ++k) {
            int idx = k * 64 + lane;
            key[k] = (idx < PN)
                ? (((uint64_t)mono_key(convf[idx]) << 32) | (uint64_t)(uint32_t)(PN - 1 - idx))
                : 0;
        }
        for (int t = 0; t < select_num; ++t) {
            uint64_t m = key[0];
            #pragma unroll
            for (int k = 1; k < NCHUNK; ++k) m = (key[k] > m) ? key[k] : m;
            m = wave_max_u64(m);
            int idx = (PN - 1) - (int)(uint32_t)m;
            if (lane == 0)
                out[(size_t)b * select_num + t] = (float)(idx + 1);   // order + 1
            if ((idx & 63) == lane) {
                int kk = idx >> 6;
                #pragma unroll
                for (int k = 0; k < NCHUNK; ++k)
                    if (k == kk) key[k] = 0;
            }
        }
    }
}

extern "C" void kernel_launch(void* const* d_in, const int* in_sizes, int n_in,
                              void* d_out, int out_size, void* d_ws, size_t ws_size,
                              hipStream_t stream) {
    (void)in_sizes; (void)n_in; (void)d_ws; (void)ws_size;
    const float* x    = (const float*)d_in[0];
    const float* kern = (const float*)d_in[1];
    // out = [patch_idx (BATCH x select) | count (BATCH x PN)], all float32.
    int select_num = (out_size - BATCH * PN) / BATCH;   // = 24 here
    mhv_kernel<<<dim3(BATCH), dim3(768), 0, stream>>>(x, kern, (float*)d_out, select_num);
}

// Round 3
// 23.478 us; speedup vs baseline: 1.6065x; 1.6065x over previous
//
#include <hip/hip_runtime.h>
#include <stdint.h>

#define BATCH 32
#define NH 12
#define SEQ 785
#define PN 784        // patch_num
#define HDIM 28       // 28*28 == 784
#define VOTE 24       // VOTE_PERHEAD
#define NCHUNK 13     // ceil(784/64)
#define NBIN 128

// Monotonic float -> uint32: k(a) > k(b) iff a > b (finite floats).
__device__ __forceinline__ uint32_t mono_key(float f) {
    uint32_t u = __float_as_uint(f);
    return (u & 0x80000000u) ? ~u : (u | 0x80000000u);
}

// Wave-parallel radix top-r select over composite keys (value desc, idx asc).
// key[c] valid iff bit c of `alive` set. Calls win(c) exactly r times.
// Keys must be distinct among alive elements (index bits guarantee this).
// 7-bit digits from SHIFT0 down to 0. Threshold bin found per-pass via
// wave suffix-scan; broadcast via ballot+shfl (no LDS). Histogram in LDS with
// __threadfence_block() fences so clear -> atomics -> readback are ordered
// even if the atomic lowers to a flat (non-DS) op.
template <int SHIFT0, typename WinF>
__device__ __forceinline__ void wave_select(const uint64_t* key, uint32_t alive,
                                            uint32_t r, uint32_t* histRow,
                                            int lane, WinF&& win) {
    static_assert(SHIFT0 % 7 == 0, "SHIFT0 must be a multiple of 7");
    constexpr int NPASS = SHIFT0 / 7 + 1;
    for (int p = 0; p < NPASS; ++p) {
        const int shift = SHIFT0 - 7 * p;
        // clear this wave's 128 bins (2 per lane)
        histRow[2 * lane]     = 0;
        histRow[2 * lane + 1] = 0;
        __threadfence_block();
        // histogram alive elements
        #pragma unroll
        for (int c = 0; c < NCHUNK; ++c)
            if (alive & (1u << c))
                atomicAdd(&histRow[(uint32_t)(key[c] >> shift) & (NBIN - 1)], 1u);
        __threadfence_block();
        uint32_t h0 = histRow[2 * lane];      // bin 2*lane
        uint32_t h1 = histRow[2 * lane + 1];  // bin 2*lane+1
        // inclusive suffix-sum of per-lane totals across the wave
        uint32_t x = h0 + h1;
        #pragma unroll
        for (int off = 1; off < 64; off <<= 1) {
            uint32_t t = __shfl_down(x, off, 64);
            if (lane + off < 64) x += t;
        }
        uint32_t tail = x - h0 - h1;          // count of digits >= 2*lane+2
        // threshold bin B = largest digit with suffix-count >= r
        uint32_t Bc = 0, rc = 0, cc = 0;
        int found = 0;
        if (tail < r && r <= tail + h1) {
            Bc = 2 * lane + 1; rc = r - tail; cc = h1; found = 1;
        } else if (tail + h1 < r && r <= tail + h1 + h0) {
            Bc = 2 * lane; rc = r - tail - h1; cc = h0; found = 1;
        }
        uint64_t m = __ballot(found);          // exactly one lane sets found
        int src = (int)(__ffsll((unsigned long long)m) - 1);
        uint32_t B    = __shfl(Bc, src, 64);
        uint32_t rnew = __shfl(rc, src, 64);
        uint32_t cb   = __shfl(cc, src, 64);
        // digits above B win; below die; bin B stays alive
        #pragma unroll
        for (int c = 0; c < NCHUNK; ++c) {
            if (alive & (1u << c)) {
                uint32_t bin = (uint32_t)(key[c] >> shift) & (NBIN - 1);
                if (bin > B)      { win(c); alive &= ~(1u << c); }
                else if (bin < B) { alive &= ~(1u << c); }
            }
        }
        r = rnew;
        if (cb == rnew) {   // all remaining alive (= bin B) are winners
            #pragma unroll
            for (int c = 0; c < NCHUNK; ++c)
                if (alive & (1u << c)) win(c);
            return;
        }
    }
}

__launch_bounds__(768, 1)
__global__ void mhv_kernel(const float* __restrict__ x,
                           const float* __restrict__ kern,
                           float* __restrict__ out,
                           int select_num) {
    const int b    = blockIdx.x;
    const int tid  = threadIdx.x;
    const int w    = tid >> 6;
    const int lane = tid & 63;

    __shared__ uint32_t cnt[PN];
    __shared__ float    convf[PN];
    __shared__ uint32_t hist[NH][NBIN];
    __shared__ uint64_t wkey[64];
    __shared__ int      wcnt;
    __shared__ float    kl[9];

    for (int i = tid; i < PN; i += 768) cnt[i] = 0;
    if (tid < 9) kl[tid] = kern[tid];
    if (tid == 0) wcnt = 0;
    if (tid < 64) wkey[tid] = 0;
    __syncthreads();

    // ---- Phase A: per-head (wave == head) top-24 vote via radix select ----
    {
        const size_t base = ((size_t)(b * NH + w) * SEQ) * SEQ + 1;  // x[b,h,0,1]
        uint64_t key[NCHUNK];
        #pragma unroll
        for (int c = 0; c < NCHUNK; ++c) {
            int idx = c * 64 + lane;
            float v = (idx < PN) ? x[base + idx] : 0.0f;
            key[c] = ((uint64_t)mono_key(v) << 10) |
                     ((uint32_t)(PN - 1 - idx) & 1023u);
        }
        uint32_t alive = (lane < (PN - 12 * 64)) ? 0x1FFFu : 0x0FFFu;
        wave_select<35>(key, alive, VOTE, hist[w], lane,
            [&](int c) { atomicAdd(&cnt[c * 64 + lane], 1u); });
    }
    __syncthreads();

    // ---- Phase B: 3x3 SAME conv on 28x28 count grid; write output 1 ----
    float* out1 = out + BATCH * select_num;
    for (int i = tid; i < PN; i += 768) {
        int y  = i / HDIM;
        int xx = i - y * HDIM;
        float s = 0.0f;
        #pragma unroll
        for (int dy = 0; dy < 3; ++dy) {
            int yy = y + dy - 1;
            if (yy < 0 || yy >= HDIM) continue;
            #pragma unroll
            for (int dx = 0; dx < 3; ++dx) {
                int xc = xx + dx - 1;
                if (xc < 0 || xc >= HDIM) continue;
                s += kl[dy * 3 + dx] * (float)cnt[yy * HDIM + xc];
            }
        }
        convf[i] = s;
        out1[(size_t)b * PN + i] = s;
    }
    __syncthreads();

    // ---- Phase C: top-select_num of conv (value desc, idx asc) on wave 0 ----
    if (w == 0) {
        uint64_t key[NCHUNK];
        #pragma unroll
        for (int c = 0; c < NCHUNK; ++c) {
            int idx = c * 64 + lane;
            // conv values are exact small non-negative ints (<= 192): 21-bit key
            int vi = (idx < PN) ? (int)convf[idx] : 0;
            key[c] = ((uint64_t)(uint32_t)vi << 10) |
                     ((uint32_t)(PN - 1 - idx) & 1023u);
        }
        uint32_t alive = (lane < (PN - 12 * 64)) ? 0x1FFFu : 0x0FFFu;
        wave_select<14>(key, alive, (uint32_t)select_num, hist[0], lane,
            [&](int c) { int s = atomicAdd(&wcnt, 1); wkey[s] = key[c]; });
        __threadfence_block();
        // rank the select_num winners (tiny pairwise pass), write output 0
        if (lane < select_num) {
            uint64_t mk = wkey[lane];
            int rank = 0;
            for (int m2 = 0; m2 < select_num; ++m2) rank += (wkey[m2] > mk) ? 1 : 0;
            int idx = PN - 1 - (int)(mk & 1023u);
            out[(size_t)b * select_num + rank] = (float)(idx + 1);
        }
    }
}

extern "C" void kernel_launch(void* const* d_in, const int* in_sizes, int n_in,
                              void* d_out, int out_size, void* d_ws, size_t ws_size,
                              hipStream_t stream) {
    (void)in_sizes; (void)n_in; (void)d_ws; (void)ws_size;
    const float* x    = (const float*)d_in[0];
    const float* kern = (const float*)d_in[1];
    int select_num = (out_size - BATCH * PN) / BATCH;   // = 24
    mhv_kernel<<<dim3(BATCH), dim3(768), 0, stream>>>(x, kern, (float*)d_out, select_num);
}